// Round 4
// baseline (149.828 us; speedup 1.0000x reference)
//
#include <hip/hip_runtime.h>
#include <cstdint>
#include <cstddef>

#define NUSERS 100000
#define BB 16384

static __device__ __forceinline__ float readlane_f(float v, int l) {
    return __uint_as_float(__builtin_amdgcn_readlane(__float_as_uint(v), l));
}
static __device__ __forceinline__ int readlane_i(int v, int l) {
    return __builtin_amdgcn_readlane(v, l);
}

// ---------------- K0: per-user attention score Q[u] = tanh(f[u]@wg1+bg1)@wg2 + bg2
__global__ __launch_bounds__(256) void k0_scores(
    const float* __restrict__ features, const float* __restrict__ wg1,
    const float* __restrict__ bg1, const float* __restrict__ wg2,
    const float* __restrict__ bg2, float* __restrict__ Q)
{
    __shared__ float frow[16 * 68];   // 16 user rows, padded
    __shared__ float wg1t[16 * 68];   // wg1 transposed [k][d], padded
    const int tid = threadIdx.x;
    const int blk = blockIdx.x;
    const float* fbase = features + (size_t)blk * 16 * 64;
    for (int i = tid; i < 1024; i += 256) {
        frow[(i >> 6) * 68 + (i & 63)] = fbase[i];
        wg1t[(i & 15) * 68 + (i >> 4)] = wg1[i];
    }
    __syncthreads();
    const int k = tid & 15, ul = tid >> 4;
    float x = bg1[k];
    #pragma unroll
    for (int d4 = 0; d4 < 16; ++d4) {
        const float4 f = *(const float4*)&frow[ul * 68 + d4 * 4];
        const float4 w = *(const float4*)&wg1t[k * 68 + d4 * 4];
        x += f.x * w.x + f.y * w.y + f.z * w.z + f.w * w.w;
    }
    float xx = fminf(fmaxf(x, -9.f), 9.f);
    float e2 = __expf(2.f * xx);
    float th = (e2 - 1.f) / (e2 + 1.f);
    float t = th * wg2[k];
    t += __shfl_xor(t, 1);
    t += __shfl_xor(t, 2);
    t += __shfl_xor(t, 4);
    t += __shfl_xor(t, 8);
    if (k == 0) Q[blk * 16 + ul] = t + bg2[0];
}

// ---------------- K1: attention-pool + masked means -> comb[B][128]
// Lane layout for gathers: grp = lane>>4 (row slot 0..3), sub = lane&15 (dim quad).
// One global_load_dwordx4 fetches 4 feature rows (1024B) at once.
__global__ __launch_bounds__(256) void k1_fuse(
    const int* __restrict__ nodes, const int* __restrict__ hist_u,
    const int* __restrict__ hist_r, const int* __restrict__ hist_m,
    const int* __restrict__ soc_a, const int* __restrict__ soc_m,
    const float* __restrict__ features, const float* __restrict__ r_embed,
    const float* __restrict__ Q, float* __restrict__ comb)
{
    __shared__ int hcomp[4][64];   // compacted history byte-offsets per wave
    __shared__ int scomp[4][32];   // compacted social byte-offsets per wave

    const int tid = threadIdx.x;
    const int lane = tid & 63;
    const int wv = tid >> 6;
    const int e = blockIdx.x * 4 + wv;
    const int sub = lane & 15;
    const int grp = lane >> 4;
    const char* fbase = (const char*)features;

    // zero-init compaction buffers so tail slots hold a safe offset (row 0)
    hcomp[wv][lane] = 0;
    scomp[wv][lane & 31] = 0;

    // rating-embedding dim-quads (5 rows), per-lane float4 for dims sub*4..+3
    const float4* re4p = (const float4*)r_embed;
    const float4 re0 = re4p[0 * 16 + sub];
    const float4 re1 = re4p[1 * 16 + sub];
    const float4 re2 = re4p[2 * 16 + sub];
    const float4 re3 = re4p[3 * 16 + sub];
    const float4 re4 = re4p[4 * 16 + sub];

    // ---- index loads ----
    int nd = (lane < 8) ? nodes[e * 8 + lane] : 0;
    int hu = 0, hr = 0, hmv = 0;
    if (lane < 50) {
        hu  = hist_u[e * 50 + lane];
        hr  = hist_r[e * 50 + lane];
        hmv = hist_m[e * 50 + lane];
    }
    int sa = 0, sk = 0;
    if (lane < 32) {
        sa = soc_a[e * 32 + lane];
        sk = soc_m[e * 32 + lane];
    }

    // ---- rank-compaction of active byte-offsets into LDS ----
    uint64_t hb = __ballot(hmv != 0);
    const int hc = (int)__popcll(hb);
    int hrank = (int)__popcll(hb & ((1ull << lane) - 1));
    if (hmv) hcomp[wv][hrank] = hu << 8;

    uint64_t sbm = __ballot(sk != 0);
    const int scn = (int)__popcll(sbm);
    int srank = (int)__popcll(sbm & ((1ull << lane) - 1));
    if (sk) scomp[wv][srank] = sa << 8;

    // ---- rating counts (replaces per-gather remb adds) ----
    const int c0 = (int)__popcll(__ballot(hmv && hr == 0));
    const int c1 = (int)__popcll(__ballot(hmv && hr == 1));
    const int c2 = (int)__popcll(__ballot(hmv && hr == 2));
    const int c3 = (int)__popcll(__ballot(hmv && hr == 3));
    const int c4 = (int)__popcll(__ballot(hmv && hr == 4));

    // ---- softmax over 8 group logits (lanes 0..7) ----
    float sc = (lane < 8) ? Q[nd] : -1e30f;
    float mx = sc;
    mx = fmaxf(mx, __shfl_xor(mx, 1));
    mx = fmaxf(mx, __shfl_xor(mx, 2));
    mx = fmaxf(mx, __shfl_xor(mx, 4));
    float ex = __expf(sc - mx);
    float sm = ex;
    sm += __shfl_xor(sm, 1);
    sm += __shfl_xor(sm, 2);
    sm += __shfl_xor(sm, 4);
    float al = ex / sm;                 // valid on lanes 0..7

    // ---- read back compacted lists (lane i holds entry i) ----
    int hpk = hcomp[wv][lane];
    int spk = scomp[wv][lane & 31];

    // ---- group attention: 8 rows in 2x 4-row gathers, alpha-weighted ----
    float4 sf4;
    {
        float a0 = __shfl(al, grp);
        int   u0 = __shfl(nd, grp);
        float a1 = __shfl(al, 4 + grp);
        int   u1 = __shfl(nd, 4 + grp);
        const float4 v0 = *(const float4*)(fbase + ((unsigned)u0 << 8) + sub * 16);
        const float4 v1 = *(const float4*)(fbase + ((unsigned)u1 << 8) + sub * 16);
        sf4.x = a0 * v0.x + a1 * v1.x;
        sf4.y = a0 * v0.y + a1 * v1.y;
        sf4.z = a0 * v0.z + a1 * v1.z;
        sf4.w = a0 * v0.w + a1 * v1.w;
    }

    // ---- history: 4 rows per dwordx4 ----
    float4 ha4 = {0.f, 0.f, 0.f, 0.f};
    const int hfull = hc & ~3;
    for (int i = 0; i < hfull; i += 4) {
        int off = __shfl(hpk, i + grp);
        const float4 v = *(const float4*)(fbase + (unsigned)off + sub * 16);
        ha4.x += v.x; ha4.y += v.y; ha4.z += v.z; ha4.w += v.w;
    }
    if (hfull < hc) {
        int idx = hfull + grp;
        int off = __shfl(hpk, idx);
        float w = (idx < hc) ? 1.f : 0.f;
        const float4 v = *(const float4*)(fbase + (unsigned)off + sub * 16);
        ha4.x += w * v.x; ha4.y += w * v.y; ha4.z += w * v.z; ha4.w += w * v.w;
    }

    // ---- social: 4 rows per dwordx4 ----
    float4 sa4 = {0.f, 0.f, 0.f, 0.f};
    const int sfull = scn & ~3;
    for (int i = 0; i < sfull; i += 4) {
        int off = __shfl(spk, i + grp);
        const float4 v = *(const float4*)(fbase + (unsigned)off + sub * 16);
        sa4.x += v.x; sa4.y += v.y; sa4.z += v.z; sa4.w += v.w;
    }
    if (sfull < scn) {
        int idx = sfull + grp;
        int off = __shfl(spk, idx);
        float w = (idx < scn) ? 1.f : 0.f;
        const float4 v = *(const float4*)(fbase + (unsigned)off + sub * 16);
        sa4.x += w * v.x; sa4.y += w * v.y; sa4.z += w * v.z; sa4.w += w * v.w;
    }

    // ---- cross-group reduction (sum row-slot partials; all lanes end equal) ----
#define XRED(v4)                                            \
    v4.x += __shfl_xor(v4.x, 16); v4.x += __shfl_xor(v4.x, 32); \
    v4.y += __shfl_xor(v4.y, 16); v4.y += __shfl_xor(v4.y, 32); \
    v4.z += __shfl_xor(v4.z, 16); v4.z += __shfl_xor(v4.z, 32); \
    v4.w += __shfl_xor(v4.w, 16); v4.w += __shfl_xor(v4.w, 32);
    XRED(sf4)
    XRED(ha4)
    XRED(sa4)
#undef XRED

    // ---- rating-count correction + means ----
    float f0 = (float)c0, f1 = (float)c1, f2 = (float)c2, f3 = (float)c3, f4 = (float)c4;
    ha4.x += f0 * re0.x + f1 * re1.x + f2 * re2.x + f3 * re3.x + f4 * re4.x;
    ha4.y += f0 * re0.y + f1 * re1.y + f2 * re2.y + f3 * re3.y + f4 * re4.y;
    ha4.z += f0 * re0.z + f1 * re1.z + f2 * re2.z + f3 * re3.z + f4 * re4.z;
    ha4.w += f0 * re0.w + f1 * re1.w + f2 * re2.w + f3 * re3.w + f4 * re4.w;

    const float ih = 1.f / (float)hc;      // hc >= 1 (mask[:,0]=True)
    const float is = 1.f / (float)scn;     // scn >= 1
    float4 nb4;
    nb4.x = 0.5f * (ha4.x * ih + sa4.x * is);
    nb4.y = 0.5f * (ha4.y * ih + sa4.y * is);
    nb4.z = 0.5f * (ha4.z * ih + sa4.z * is);
    nb4.w = 0.5f * (ha4.w * ih + sa4.w * is);

    // ---- store comb[e][0:64]=self, comb[e][64:128]=neigh ----
    if (grp == 0) *(float4*)(comb + (size_t)e * 128 + sub * 4) = sf4;
    if (grp == 1) *(float4*)(comb + (size_t)e * 128 + 64 + sub * 4) = nb4;
}

// ---------------- K2: out = relu(comb[B][128] @ w1[128][64] + b1)
__global__ __launch_bounds__(256) void k2_gemm(
    const float* __restrict__ comb, const float* __restrict__ w1,
    const float* __restrict__ b1, float* __restrict__ out)
{
    __shared__ float w1s[128 * 64];
    __shared__ float4 ct4[32 * 32];   // 32 rows x 128 floats
    const int tid = threadIdx.x;
    const float4* w14 = (const float4*)w1;
    float4* w1s4 = (float4*)w1s;
    for (int i = tid; i < 2048; i += 256) w1s4[i] = w14[i];
    const float4* c4 = (const float4*)(comb + (size_t)blockIdx.x * 32 * 128);
    for (int i = tid; i < 1024; i += 256) ct4[i] = c4[i];
    __syncthreads();

    const int n = tid & 63, wv = tid >> 6;
    const float bv = b1[n];
    float acc[8] = {bv, bv, bv, bv, bv, bv, bv, bv};
    #pragma unroll
    for (int k4 = 0; k4 < 32; ++k4) {
        float w0  = w1s[(k4 * 4 + 0) * 64 + n];
        float w1v = w1s[(k4 * 4 + 1) * 64 + n];
        float w2v = w1s[(k4 * 4 + 2) * 64 + n];
        float w3v = w1s[(k4 * 4 + 3) * 64 + n];
        #pragma unroll
        for (int i = 0; i < 8; ++i) {
            float4 cv = ct4[(wv * 8 + i) * 32 + k4];
            acc[i] += cv.x * w0 + cv.y * w1v + cv.z * w2v + cv.w * w3v;
        }
    }
    const int row0 = blockIdx.x * 32 + wv * 8;
    #pragma unroll
    for (int i = 0; i < 8; ++i)
        out[(size_t)(row0 + i) * 64 + n] = fmaxf(acc[i], 0.f);
}

extern "C" void kernel_launch(void* const* d_in, const int* in_sizes, int n_in,
                              void* d_out, int out_size, void* d_ws, size_t ws_size,
                              hipStream_t stream)
{
    const int*   nodes    = (const int*)d_in[0];
    const int*   hu       = (const int*)d_in[1];
    const int*   hr       = (const int*)d_in[2];
    const int*   hm       = (const int*)d_in[3];
    const int*   sa       = (const int*)d_in[4];
    const int*   smk      = (const int*)d_in[5];
    const float* features = (const float*)d_in[6];
    const float* r_embed  = (const float*)d_in[7];
    const float* wg1      = (const float*)d_in[8];
    const float* bg1      = (const float*)d_in[9];
    const float* wg2      = (const float*)d_in[10];
    const float* bg2      = (const float*)d_in[11];
    const float* w1       = (const float*)d_in[12];
    const float* b1       = (const float*)d_in[13];
    float* out = (float*)d_out;

    float* Q    = (float*)d_ws;          // 100000 floats (rounded region 131072)
    float* comb = Q + 131072;            // 16384*128 floats = 8 MB

    k0_scores<<<NUSERS / 16, 256, 0, stream>>>(features, wg1, bg1, wg2, bg2, Q);
    k1_fuse<<<BB / 4, 256, 0, stream>>>(nodes, hu, hr, hm, sa, smk,
                                        features, r_embed, Q, comb);
    k2_gemm<<<BB / 32, 256, 0, stream>>>(comb, w1, b1, out);
}

// Round 5
// 141.479 us; speedup vs baseline: 1.0590x; 1.0590x over previous
//
#include <hip/hip_runtime.h>
#include <cstdint>
#include <cstddef>

#define NUSERS 100000
#define BB 16384

static __device__ __forceinline__ int readlane_i(int v, int l) {
    return __builtin_amdgcn_readlane(v, l);
}
static __device__ __forceinline__ unsigned short f2bf(float x) {
    unsigned u = __float_as_uint(x);
    u += 0x7FFF + ((u >> 16) & 1);          // round-to-nearest-even
    return (unsigned short)(u >> 16);
}
static __device__ __forceinline__ float4 bf4_to_f4(ushort4 h) {
    float4 r;
    r.x = __uint_as_float((unsigned)h.x << 16);
    r.y = __uint_as_float((unsigned)h.y << 16);
    r.z = __uint_as_float((unsigned)h.z << 16);
    r.w = __uint_as_float((unsigned)h.w << 16);
    return r;
}

// ---------------- K0: per-user attention score Q[u] AND bf16 feature table
__global__ __launch_bounds__(256) void k0_scores(
    const float* __restrict__ features, const float* __restrict__ wg1,
    const float* __restrict__ bg1, const float* __restrict__ wg2,
    const float* __restrict__ bg2, float* __restrict__ Q,
    unsigned short* __restrict__ fbf)
{
    __shared__ float frow[16 * 68];   // 16 user rows, padded
    __shared__ float wg1t[16 * 68];   // wg1 transposed [k][d], padded
    const int tid = threadIdx.x;
    const int blk = blockIdx.x;
    const float* fbase = features + (size_t)blk * 16 * 64;
    for (int i = tid; i < 1024; i += 256) {
        frow[(i >> 6) * 68 + (i & 63)] = fbase[i];
        wg1t[(i & 15) * 68 + (i >> 4)] = wg1[i];
    }
    __syncthreads();

    // emit bf16 copy of these 16 rows (coalesced 8B/lane)
    {
        const int base = tid * 4;                 // 0..1020, same row for all 4
        const int row = base >> 6, col = base & 63;
        ushort4 o;
        o.x = f2bf(frow[row * 68 + col + 0]);
        o.y = f2bf(frow[row * 68 + col + 1]);
        o.z = f2bf(frow[row * 68 + col + 2]);
        o.w = f2bf(frow[row * 68 + col + 3]);
        *(ushort4*)(fbf + (size_t)blk * 1024 + base) = o;
    }

    const int k = tid & 15, ul = tid >> 4;
    float x = bg1[k];
    #pragma unroll
    for (int d4 = 0; d4 < 16; ++d4) {
        const float4 f = *(const float4*)&frow[ul * 68 + d4 * 4];
        const float4 w = *(const float4*)&wg1t[k * 68 + d4 * 4];
        x += f.x * w.x + f.y * w.y + f.z * w.z + f.w * w.w;
    }
    float xx = fminf(fmaxf(x, -9.f), 9.f);
    float e2 = __expf(2.f * xx);
    float th = (e2 - 1.f) / (e2 + 1.f);
    float t = th * wg2[k];
    t += __shfl_xor(t, 1);
    t += __shfl_xor(t, 2);
    t += __shfl_xor(t, 4);
    t += __shfl_xor(t, 8);
    if (k == 0) Q[blk * 16 + ul] = t + bg2[0];
}

// ---------------- K1: attention-pool + masked means -> comb[B][128]
// Gathers read the bf16 table: row = 128B. Lane layout: grp = lane>>4 (row
// slot 0..3), sub = lane&15 (dim quad). One ushort4 load = 4 rows/instr.
__global__ __launch_bounds__(256) void k1_fuse(
    const int* __restrict__ nodes, const int* __restrict__ hist_u,
    const int* __restrict__ hist_r, const int* __restrict__ hist_m,
    const int* __restrict__ soc_a, const int* __restrict__ soc_m,
    const unsigned short* __restrict__ fbf, const float* __restrict__ r_embed,
    const float* __restrict__ Q, float* __restrict__ comb)
{
    __shared__ int hcomp[4][64];   // compacted history byte-offsets per wave
    __shared__ int scomp[4][32];   // compacted social byte-offsets per wave

    const int tid = threadIdx.x;
    const int lane = tid & 63;
    const int wv = tid >> 6;
    const int e = blockIdx.x * 4 + wv;
    const int sub = lane & 15;
    const int grp = lane >> 4;
    const char* fb = (const char*)fbf;

    // zero-init compaction buffers so tail slots hold a safe offset (row 0)
    hcomp[wv][lane] = 0;
    scomp[wv][lane & 31] = 0;

    // rating-embedding dim-quads (5 rows, f32), dims sub*4..+3
    const float4* re4p = (const float4*)r_embed;
    const float4 re0 = re4p[0 * 16 + sub];
    const float4 re1 = re4p[1 * 16 + sub];
    const float4 re2 = re4p[2 * 16 + sub];
    const float4 re3 = re4p[3 * 16 + sub];
    const float4 re4 = re4p[4 * 16 + sub];

    // ---- index loads ----
    int nd = (lane < 8) ? nodes[e * 8 + lane] : 0;
    int hu = 0, hr = 0, hmv = 0;
    if (lane < 50) {
        hu  = hist_u[e * 50 + lane];
        hr  = hist_r[e * 50 + lane];
        hmv = hist_m[e * 50 + lane];
    }
    int sa = 0, sk = 0;
    if (lane < 32) {
        sa = soc_a[e * 32 + lane];
        sk = soc_m[e * 32 + lane];
    }

    // ---- rank-compaction of active byte-offsets into LDS ----
    uint64_t hb = __ballot(hmv != 0);
    const int hc = (int)__popcll(hb);
    int hrank = (int)__popcll(hb & ((1ull << lane) - 1));
    if (hmv) hcomp[wv][hrank] = hu << 7;          // bf16 row byte offset

    uint64_t sbm = __ballot(sk != 0);
    const int scn = (int)__popcll(sbm);
    int srank = (int)__popcll(sbm & ((1ull << lane) - 1));
    if (sk) scomp[wv][srank] = sa << 7;

    // ---- rating counts (replaces per-gather remb adds) ----
    const int c0 = (int)__popcll(__ballot(hmv && hr == 0));
    const int c1 = (int)__popcll(__ballot(hmv && hr == 1));
    const int c2 = (int)__popcll(__ballot(hmv && hr == 2));
    const int c3 = (int)__popcll(__ballot(hmv && hr == 3));
    const int c4 = (int)__popcll(__ballot(hmv && hr == 4));

    // ---- softmax over 8 group logits (lanes 0..7) ----
    float sc = (lane < 8) ? Q[nd] : -1e30f;
    float mx = sc;
    mx = fmaxf(mx, __shfl_xor(mx, 1));
    mx = fmaxf(mx, __shfl_xor(mx, 2));
    mx = fmaxf(mx, __shfl_xor(mx, 4));
    float ex = __expf(sc - mx);
    float sm = ex;
    sm += __shfl_xor(sm, 1);
    sm += __shfl_xor(sm, 2);
    sm += __shfl_xor(sm, 4);
    float al = ex / sm;                 // valid on lanes 0..7

    // ---- read back compacted lists (lane i holds entry i) ----
    int hpk = hcomp[wv][lane];
    int spk = scomp[wv][lane & 31];

    // ---- group attention: 8 rows in 2x 4-row gathers, alpha-weighted ----
    float4 sf4;
    {
        float a0 = __shfl(al, grp);
        int   u0 = __shfl(nd, grp);
        float a1 = __shfl(al, 4 + grp);
        int   u1 = __shfl(nd, 4 + grp);
        const float4 v0 = bf4_to_f4(*(const ushort4*)(fb + ((unsigned)u0 << 7) + sub * 8));
        const float4 v1 = bf4_to_f4(*(const ushort4*)(fb + ((unsigned)u1 << 7) + sub * 8));
        sf4.x = a0 * v0.x + a1 * v1.x;
        sf4.y = a0 * v0.y + a1 * v1.y;
        sf4.z = a0 * v0.z + a1 * v1.z;
        sf4.w = a0 * v0.w + a1 * v1.w;
    }

    // ---- history: 4 rows per ushort4 load ----
    float4 ha4 = {0.f, 0.f, 0.f, 0.f};
    const int hfull = hc & ~3;
    for (int i = 0; i < hfull; i += 4) {
        int off = __shfl(hpk, i + grp);
        const float4 v = bf4_to_f4(*(const ushort4*)(fb + (unsigned)off + sub * 8));
        ha4.x += v.x; ha4.y += v.y; ha4.z += v.z; ha4.w += v.w;
    }
    if (hfull < hc) {
        int idx = hfull + grp;
        int off = __shfl(hpk, idx);
        float w = (idx < hc) ? 1.f : 0.f;
        const float4 v = bf4_to_f4(*(const ushort4*)(fb + (unsigned)off + sub * 8));
        ha4.x += w * v.x; ha4.y += w * v.y; ha4.z += w * v.z; ha4.w += w * v.w;
    }

    // ---- social: 4 rows per ushort4 load ----
    float4 sa4 = {0.f, 0.f, 0.f, 0.f};
    const int sfull = scn & ~3;
    for (int i = 0; i < sfull; i += 4) {
        int off = __shfl(spk, i + grp);
        const float4 v = bf4_to_f4(*(const ushort4*)(fb + (unsigned)off + sub * 8));
        sa4.x += v.x; sa4.y += v.y; sa4.z += v.z; sa4.w += v.w;
    }
    if (sfull < scn) {
        int idx = sfull + grp;
        int off = __shfl(spk, idx);
        float w = (idx < scn) ? 1.f : 0.f;
        const float4 v = bf4_to_f4(*(const ushort4*)(fb + (unsigned)off + sub * 8));
        sa4.x += w * v.x; sa4.y += w * v.y; sa4.z += w * v.z; sa4.w += w * v.w;
    }

    // ---- cross-group reduction (sum row-slot partials; all lanes end equal) ----
#define XRED(v4)                                            \
    v4.x += __shfl_xor(v4.x, 16); v4.x += __shfl_xor(v4.x, 32); \
    v4.y += __shfl_xor(v4.y, 16); v4.y += __shfl_xor(v4.y, 32); \
    v4.z += __shfl_xor(v4.z, 16); v4.z += __shfl_xor(v4.z, 32); \
    v4.w += __shfl_xor(v4.w, 16); v4.w += __shfl_xor(v4.w, 32);
    XRED(sf4)
    XRED(ha4)
    XRED(sa4)
#undef XRED

    // ---- rating-count correction + means ----
    float f0 = (float)c0, f1 = (float)c1, f2 = (float)c2, f3 = (float)c3, f4 = (float)c4;
    ha4.x += f0 * re0.x + f1 * re1.x + f2 * re2.x + f3 * re3.x + f4 * re4.x;
    ha4.y += f0 * re0.y + f1 * re1.y + f2 * re2.y + f3 * re3.y + f4 * re4.y;
    ha4.z += f0 * re0.z + f1 * re1.z + f2 * re2.z + f3 * re3.z + f4 * re4.z;
    ha4.w += f0 * re0.w + f1 * re1.w + f2 * re2.w + f3 * re3.w + f4 * re4.w;

    const float ih = 1.f / (float)hc;      // hc >= 1 (mask[:,0]=True)
    const float is = 1.f / (float)scn;     // scn >= 1
    float4 nb4;
    nb4.x = 0.5f * (ha4.x * ih + sa4.x * is);
    nb4.y = 0.5f * (ha4.y * ih + sa4.y * is);
    nb4.z = 0.5f * (ha4.z * ih + sa4.z * is);
    nb4.w = 0.5f * (ha4.w * ih + sa4.w * is);

    // ---- store comb[e][0:64]=self, comb[e][64:128]=neigh ----
    if (grp == 0) *(float4*)(comb + (size_t)e * 128 + sub * 4) = sf4;
    if (grp == 1) *(float4*)(comb + (size_t)e * 128 + 64 + sub * 4) = nb4;
}

// ---------------- K2: out = relu(comb[B][128] @ w1[128][64] + b1)
__global__ __launch_bounds__(256) void k2_gemm(
    const float* __restrict__ comb, const float* __restrict__ w1,
    const float* __restrict__ b1, float* __restrict__ out)
{
    __shared__ float w1s[128 * 64];
    __shared__ float4 ct4[32 * 32];   // 32 rows x 128 floats
    const int tid = threadIdx.x;
    const float4* w14 = (const float4*)w1;
    float4* w1s4 = (float4*)w1s;
    for (int i = tid; i < 2048; i += 256) w1s4[i] = w14[i];
    const float4* c4 = (const float4*)(comb + (size_t)blockIdx.x * 32 * 128);
    for (int i = tid; i < 1024; i += 256) ct4[i] = c4[i];
    __syncthreads();

    const int n = tid & 63, wv = tid >> 6;
    const float bv = b1[n];
    float acc[8] = {bv, bv, bv, bv, bv, bv, bv, bv};
    #pragma unroll
    for (int k4 = 0; k4 < 32; ++k4) {
        float w0  = w1s[(k4 * 4 + 0) * 64 + n];
        float w1v = w1s[(k4 * 4 + 1) * 64 + n];
        float w2v = w1s[(k4 * 4 + 2) * 64 + n];
        float w3v = w1s[(k4 * 4 + 3) * 64 + n];
        #pragma unroll
        for (int i = 0; i < 8; ++i) {
            float4 cv = ct4[(wv * 8 + i) * 32 + k4];
            acc[i] += cv.x * w0 + cv.y * w1v + cv.z * w2v + cv.w * w3v;
        }
    }
    const int row0 = blockIdx.x * 32 + wv * 8;
    #pragma unroll
    for (int i = 0; i < 8; ++i)
        out[(size_t)(row0 + i) * 64 + n] = fmaxf(acc[i], 0.f);
}

extern "C" void kernel_launch(void* const* d_in, const int* in_sizes, int n_in,
                              void* d_out, int out_size, void* d_ws, size_t ws_size,
                              hipStream_t stream)
{
    const int*   nodes    = (const int*)d_in[0];
    const int*   hu       = (const int*)d_in[1];
    const int*   hr       = (const int*)d_in[2];
    const int*   hm       = (const int*)d_in[3];
    const int*   sa       = (const int*)d_in[4];
    const int*   smk      = (const int*)d_in[5];
    const float* features = (const float*)d_in[6];
    const float* r_embed  = (const float*)d_in[7];
    const float* wg1      = (const float*)d_in[8];
    const float* bg1      = (const float*)d_in[9];
    const float* wg2      = (const float*)d_in[10];
    const float* bg2      = (const float*)d_in[11];
    const float* w1       = (const float*)d_in[12];
    const float* b1       = (const float*)d_in[13];
    float* out = (float*)d_out;

    float*          Q    = (float*)d_ws;                    // 131072 floats (512 KB)
    unsigned short* fbf  = (unsigned short*)(Q + 131072);   // 100000*64 bf16 = 12.8 MB
    float*          comb = (float*)(fbf + (size_t)NUSERS * 64);  // 8 MB

    k0_scores<<<NUSERS / 16, 256, 0, stream>>>(features, wg1, bg1, wg2, bg2, Q, fbf);
    k1_fuse<<<BB / 4, 256, 0, stream>>>(nodes, hu, hr, hm, sa, smk,
                                        fbf, r_embed, Q, comb);
    k2_gemm<<<BB / 32, 256, 0, stream>>>(comb, w1, b1, out);
}

// Round 6
// 139.852 us; speedup vs baseline: 1.0713x; 1.0116x over previous
//
#include <hip/hip_runtime.h>
#include <cstdint>
#include <cstddef>

#define NUSERS 100000
#define BB 16384

static __device__ __forceinline__ unsigned short f2bf(float x) {
    unsigned u = __float_as_uint(x);
    u += 0x7FFF + ((u >> 16) & 1);          // round-to-nearest-even
    return (unsigned short)(u >> 16);
}
static __device__ __forceinline__ float4 bf4_to_f4(ushort4 h) {
    float4 r;
    r.x = __uint_as_float((unsigned)h.x << 16);
    r.y = __uint_as_float((unsigned)h.y << 16);
    r.z = __uint_as_float((unsigned)h.z << 16);
    r.w = __uint_as_float((unsigned)h.w << 16);
    return r;
}

// ---------------- K0: per-user attention score Q[u] AND bf16 feature table
__global__ __launch_bounds__(256) void k0_scores(
    const float* __restrict__ features, const float* __restrict__ wg1,
    const float* __restrict__ bg1, const float* __restrict__ wg2,
    const float* __restrict__ bg2, float* __restrict__ Q,
    unsigned short* __restrict__ fbf)
{
    __shared__ float frow[16 * 68];   // 16 user rows, padded
    __shared__ float wg1t[16 * 68];   // wg1 transposed [k][d], padded
    const int tid = threadIdx.x;
    const int blk = blockIdx.x;
    const float* fbase = features + (size_t)blk * 16 * 64;
    for (int i = tid; i < 1024; i += 256) {
        frow[(i >> 6) * 68 + (i & 63)] = fbase[i];
        wg1t[(i & 15) * 68 + (i >> 4)] = wg1[i];
    }
    __syncthreads();

    // emit bf16 copy of these 16 rows (coalesced 8B/lane)
    {
        const int base = tid * 4;                 // 0..1020, same row for all 4
        const int row = base >> 6, col = base & 63;
        ushort4 o;
        o.x = f2bf(frow[row * 68 + col + 0]);
        o.y = f2bf(frow[row * 68 + col + 1]);
        o.z = f2bf(frow[row * 68 + col + 2]);
        o.w = f2bf(frow[row * 68 + col + 3]);
        *(ushort4*)(fbf + (size_t)blk * 1024 + base) = o;
    }

    const int k = tid & 15, ul = tid >> 4;
    float x = bg1[k];
    #pragma unroll
    for (int d4 = 0; d4 < 16; ++d4) {
        const float4 f = *(const float4*)&frow[ul * 68 + d4 * 4];
        const float4 w = *(const float4*)&wg1t[k * 68 + d4 * 4];
        x += f.x * w.x + f.y * w.y + f.z * w.z + f.w * w.w;
    }
    float xx = fminf(fmaxf(x, -9.f), 9.f);
    float e2 = __expf(2.f * xx);
    float th = (e2 - 1.f) / (e2 + 1.f);
    float t = th * wg2[k];
    t += __shfl_xor(t, 1);
    t += __shfl_xor(t, 2);
    t += __shfl_xor(t, 4);
    t += __shfl_xor(t, 8);
    if (k == 0) Q[blk * 16 + ul] = t + bg2[0];
}

// ---------------- K1: attention-pool + merged weighted neighbor mean -> comb[B][128]
// Gathers read the bf16 table: row = 128B. Lane layout: grp = lane>>4 (row
// slot 0..3), sub = lane&15 (dim quad). One ushort4 load = 4 rows/instr.
// History+social merged into one (offset, weight) list; 4 loads (16 rows)
// in flight per loop iteration.
__global__ __launch_bounds__(256) void k1_fuse(
    const int* __restrict__ nodes, const int* __restrict__ hist_u,
    const int* __restrict__ hist_r, const int* __restrict__ hist_m,
    const int* __restrict__ soc_a, const int* __restrict__ soc_m,
    const unsigned short* __restrict__ fbf, const float* __restrict__ r_embed,
    const float* __restrict__ Q, float* __restrict__ comb)
{
    __shared__ int   lcomp[4][96];   // merged byte-offset list per wave
    __shared__ float wcomp[4][96];   // per-entry weight

    const int tid = threadIdx.x;
    const int lane = tid & 63;
    const int wv = tid >> 6;
    const int e = blockIdx.x * 4 + wv;
    const int sub = lane & 15;
    const int grp = lane >> 4;
    const char* fb = (const char*)fbf;

    // zero-init merged list (tail entries: offset 0 = row 0, weight 0)
    lcomp[wv][lane] = 0;
    wcomp[wv][lane] = 0.f;
    if (lane < 32) { lcomp[wv][64 + lane] = 0; wcomp[wv][64 + lane] = 0.f; }

    // rating-embedding dim-quads (5 rows, f32), dims sub*4..+3
    const float4* re4p = (const float4*)r_embed;
    const float4 re0 = re4p[0 * 16 + sub];
    const float4 re1 = re4p[1 * 16 + sub];
    const float4 re2 = re4p[2 * 16 + sub];
    const float4 re3 = re4p[3 * 16 + sub];
    const float4 re4 = re4p[4 * 16 + sub];

    // ---- index loads ----
    int nd = (lane < 8) ? nodes[e * 8 + lane] : 0;
    int hu = 0, hr = 0, hmv = 0;
    if (lane < 50) {
        hu  = hist_u[e * 50 + lane];
        hr  = hist_r[e * 50 + lane];
        hmv = hist_m[e * 50 + lane];
    }
    int sa = 0, sk = 0;
    if (lane < 32) {
        sa = soc_a[e * 32 + lane];
        sk = soc_m[e * 32 + lane];
    }

    // ---- ballots / counts ----
    uint64_t hb = __ballot(hmv != 0);
    const int hc = (int)__popcll(hb);
    int hrank = (int)__popcll(hb & ((1ull << lane) - 1));

    uint64_t sbm = __ballot(sk != 0);
    const int scn = (int)__popcll(sbm);
    int srank = (int)__popcll(sbm & ((1ull << lane) - 1));

    const float ih = 1.f / (float)hc;      // hc >= 1 (mask[:,0]=True)
    const float is = 1.f / (float)scn;     // scn >= 1
    const float hw = 0.5f * ih;
    const float sw = 0.5f * is;

    // ---- merged compaction: hist entries [0,hc), social [hc, hc+scn) ----
    if (hmv) { lcomp[wv][hrank] = hu << 7; wcomp[wv][hrank] = hw; }
    if (sk)  { lcomp[wv][hc + srank] = sa << 7; wcomp[wv][hc + srank] = sw; }

    // ---- rating counts (replaces per-gather remb adds) ----
    const int c0 = (int)__popcll(__ballot(hmv && hr == 0));
    const int c1 = (int)__popcll(__ballot(hmv && hr == 1));
    const int c2 = (int)__popcll(__ballot(hmv && hr == 2));
    const int c3 = (int)__popcll(__ballot(hmv && hr == 3));
    const int c4 = (int)__popcll(__ballot(hmv && hr == 4));

    // ---- softmax over 8 group logits (lanes 0..7) ----
    float sc = (lane < 8) ? Q[nd] : -1e30f;
    float mx = sc;
    mx = fmaxf(mx, __shfl_xor(mx, 1));
    mx = fmaxf(mx, __shfl_xor(mx, 2));
    mx = fmaxf(mx, __shfl_xor(mx, 4));
    float ex = __expf(sc - mx);
    float sm = ex;
    sm += __shfl_xor(sm, 1);
    sm += __shfl_xor(sm, 2);
    sm += __shfl_xor(sm, 4);
    float al = ex / sm;                 // valid on lanes 0..7

    // ---- read back merged list into registers (lane i <-> entry i / 64+i) ----
    int   pkA = lcomp[wv][lane];
    int   pkB = lcomp[wv][64 + (lane & 31)];
    float wgA = wcomp[wv][lane];
    float wgB = wcomp[wv][64 + (lane & 31)];
    const int n = hc + scn;             // <= 82

    // ---- group attention: 8 rows in 2x 4-row gathers, alpha-weighted ----
    float4 sf4;
    {
        float a0 = __shfl(al, grp);
        int   u0 = __shfl(nd, grp);
        float a1 = __shfl(al, 4 + grp);
        int   u1 = __shfl(nd, 4 + grp);
        const float4 v0 = bf4_to_f4(*(const ushort4*)(fb + ((unsigned)u0 << 7) + sub * 8));
        const float4 v1 = bf4_to_f4(*(const ushort4*)(fb + ((unsigned)u1 << 7) + sub * 8));
        sf4.x = a0 * v0.x + a1 * v1.x;
        sf4.y = a0 * v0.y + a1 * v1.y;
        sf4.z = a0 * v0.z + a1 * v1.z;
        sf4.w = a0 * v0.w + a1 * v1.w;
    }

    // ---- merged neighbor gather: 16 rows (4 independent loads) per iter ----
    float4 nb4 = {0.f, 0.f, 0.f, 0.f};
    for (int base = 0; base < n; base += 16) {
        #pragma unroll
        for (int j = 0; j < 4; ++j) {
            const int cbase = base + j * 4;       // uniform, 4-aligned
            int off; float w;
            if (cbase < 64) {                     // uniform branch (no straddle)
                off = __shfl(pkA, cbase + grp);
                w   = __shfl(wgA, cbase + grp);
            } else {
                off = __shfl(pkB, cbase - 64 + grp);
                w   = __shfl(wgB, cbase - 64 + grp);
            }
            const float4 v = bf4_to_f4(*(const ushort4*)(fb + (unsigned)off + sub * 8));
            nb4.x += w * v.x; nb4.y += w * v.y;
            nb4.z += w * v.z; nb4.w += w * v.w;
        }
    }

    // ---- cross-group reduction (sum row-slot partials; all lanes end equal) ----
#define XRED(v4)                                            \
    v4.x += __shfl_xor(v4.x, 16); v4.x += __shfl_xor(v4.x, 32); \
    v4.y += __shfl_xor(v4.y, 16); v4.y += __shfl_xor(v4.y, 32); \
    v4.z += __shfl_xor(v4.z, 16); v4.z += __shfl_xor(v4.z, 32); \
    v4.w += __shfl_xor(v4.w, 16); v4.w += __shfl_xor(v4.w, 32);
    XRED(sf4)
    XRED(nb4)
#undef XRED

    // ---- rating-count correction (scaled by 0.5/hc) ----
    float f0 = hw * (float)c0, f1 = hw * (float)c1, f2 = hw * (float)c2,
          f3 = hw * (float)c3, f4 = hw * (float)c4;
    nb4.x += f0 * re0.x + f1 * re1.x + f2 * re2.x + f3 * re3.x + f4 * re4.x;
    nb4.y += f0 * re0.y + f1 * re1.y + f2 * re2.y + f3 * re3.y + f4 * re4.y;
    nb4.z += f0 * re0.z + f1 * re1.z + f2 * re2.z + f3 * re3.z + f4 * re4.z;
    nb4.w += f0 * re0.w + f1 * re1.w + f2 * re2.w + f3 * re3.w + f4 * re4.w;

    // ---- store comb[e][0:64]=self, comb[e][64:128]=neigh ----
    if (grp == 0) *(float4*)(comb + (size_t)e * 128 + sub * 4) = sf4;
    if (grp == 1) *(float4*)(comb + (size_t)e * 128 + 64 + sub * 4) = nb4;
}

// ---------------- K2: out = relu(comb[B][128] @ w1[128][64] + b1)
__global__ __launch_bounds__(256) void k2_gemm(
    const float* __restrict__ comb, const float* __restrict__ w1,
    const float* __restrict__ b1, float* __restrict__ out)
{
    __shared__ float w1s[128 * 64];
    __shared__ float4 ct4[32 * 32];   // 32 rows x 128 floats
    const int tid = threadIdx.x;
    const float4* w14 = (const float4*)w1;
    float4* w1s4 = (float4*)w1s;
    for (int i = tid; i < 2048; i += 256) w1s4[i] = w14[i];
    const float4* c4 = (const float4*)(comb + (size_t)blockIdx.x * 32 * 128);
    for (int i = tid; i < 1024; i += 256) ct4[i] = c4[i];
    __syncthreads();

    const int n = tid & 63, wv = tid >> 6;
    const float bv = b1[n];
    float acc[8] = {bv, bv, bv, bv, bv, bv, bv, bv};
    #pragma unroll
    for (int k4 = 0; k4 < 32; ++k4) {
        float w0  = w1s[(k4 * 4 + 0) * 64 + n];
        float w1v = w1s[(k4 * 4 + 1) * 64 + n];
        float w2v = w1s[(k4 * 4 + 2) * 64 + n];
        float w3v = w1s[(k4 * 4 + 3) * 64 + n];
        #pragma unroll
        for (int i = 0; i < 8; ++i) {
            float4 cv = ct4[(wv * 8 + i) * 32 + k4];
            acc[i] += cv.x * w0 + cv.y * w1v + cv.z * w2v + cv.w * w3v;
        }
    }
    const int row0 = blockIdx.x * 32 + wv * 8;
    #pragma unroll
    for (int i = 0; i < 8; ++i)
        out[(size_t)(row0 + i) * 64 + n] = fmaxf(acc[i], 0.f);
}

extern "C" void kernel_launch(void* const* d_in, const int* in_sizes, int n_in,
                              void* d_out, int out_size, void* d_ws, size_t ws_size,
                              hipStream_t stream)
{
    const int*   nodes    = (const int*)d_in[0];
    const int*   hu       = (const int*)d_in[1];
    const int*   hr       = (const int*)d_in[2];
    const int*   hm       = (const int*)d_in[3];
    const int*   sa       = (const int*)d_in[4];
    const int*   smk      = (const int*)d_in[5];
    const float* features = (const float*)d_in[6];
    const float* r_embed  = (const float*)d_in[7];
    const float* wg1      = (const float*)d_in[8];
    const float* bg1      = (const float*)d_in[9];
    const float* wg2      = (const float*)d_in[10];
    const float* bg2      = (const float*)d_in[11];
    const float* w1       = (const float*)d_in[12];
    const float* b1       = (const float*)d_in[13];
    float* out = (float*)d_out;

    float*          Q    = (float*)d_ws;                    // 131072 floats (512 KB)
    unsigned short* fbf  = (unsigned short*)(Q + 131072);   // 100000*64 bf16 = 12.8 MB
    float*          comb = (float*)(fbf + (size_t)NUSERS * 64);  // 8 MB

    k0_scores<<<NUSERS / 16, 256, 0, stream>>>(features, wg1, bg1, wg2, bg2, Q, fbf);
    k1_fuse<<<BB / 4, 256, 0, stream>>>(nodes, hu, hr, hm, sa, smk,
                                        fbf, r_embed, Q, comb);
    k2_gemm<<<BB / 32, 256, 0, stream>>>(comb, w1, b1, out);
}